// Round 3
// baseline (41.327 us; speedup 1.0000x reference)
//
#include <hip/hip_runtime.h>
#include <math.h>

// Problem constants (from reference setup_inputs): z_list (P,B,D) fp32
constexpr int P = 64, B = 512, D = 1024;
constexpr int D4 = D / 4;           // 256 float4 per row
constexpr int WAVES = 8;            // waves per block in main kernel (512 thr)
constexpr int PC = P / WAVES;       // 8 p-rows per wave
constexpr int K3B = 32;             // blocks in tail kernel
constexpr int BPB = B / K3B;        // 16 b's per tail block
#define EPS 1e-8f

__device__ inline float wave_reduce_sum(float v) {
#pragma unroll
  for (int off = 1; off < 64; off <<= 1) v += __shfl_xor(v, off);
  return v;
}

__device__ inline float dot4(const float4& a, const float4& b) {
  return a.x * b.x + a.y * b.y + a.z * b.z + a.w * b.w;
}

// K_main: one block (8 waves, 512 thr) per b. Each wave streams 8 p-rows of
// z[:,b,:] (depth-1 float4 prefetch), per-row norm via wave shuffle-reduce,
// accumulates raw sum and normalized sum in registers. LDS combines the 8
// waves; block normalizes mean row -> an[b], writes Uv[b], diag[b]=Uv.an.
// Also zeroes the tail kernel's accumulators (visible after kernel boundary).
__global__ __launch_bounds__(512, 4) void k_main(const float* __restrict__ z,
                                                 float* __restrict__ an,
                                                 float* __restrict__ Uv,
                                                 float* __restrict__ diag,
                                                 float4* __restrict__ zero4) {
  const int b = blockIdx.x;
  const int t = threadIdx.x;
  const int w = t >> 6;              // wave 0..7
  const int lane = t & 63;

  // zero Sfin/Tfin/diagsum/counter region (513 float4 total, one per block +
  // tail float4 by block 0). Plain stores; kernel boundary makes them visible.
  if (t == 0) {
    zero4[b] = make_float4(0.f, 0.f, 0.f, 0.f);
    if (b == 0) zero4[512] = make_float4(0.f, 0.f, 0.f, 0.f);
  }

  __shared__ float4 lds_zs[WAVES][D4];  // 32 KB
  __shared__ float4 lds_uu[WAVES][D4];  // 32 KB
  __shared__ float red[8];

  float4 zs[4], uu[4];
#pragma unroll
  for (int k = 0; k < 4; ++k) {
    zs[k] = make_float4(0.f, 0.f, 0.f, 0.f);
    uu[k] = make_float4(0.f, 0.f, 0.f, 0.f);
  }

  // wave w handles p = w*PC .. w*PC+PC-1, row z[p][b][:]
  const size_t pstride = (size_t)B * D4;  // float4 stride between p's
  const float4* base = (const float4*)z + ((size_t)(w * PC) * B + b) * D4;

  float4 cur[4];
#pragma unroll
  for (int k = 0; k < 4; ++k) cur[k] = base[k * 64 + lane];

  for (int pp = 0; pp < PC; ++pp) {
    float4 nxt[4];
    if (pp + 1 < PC) {
      const float4* nb = base + (size_t)(pp + 1) * pstride;
#pragma unroll
      for (int k = 0; k < 4; ++k) nxt[k] = nb[k * 64 + lane];
    } else {
#pragma unroll
      for (int k = 0; k < 4; ++k) nxt[k] = cur[k];
    }

    float ss = 0.f;
#pragma unroll
    for (int k = 0; k < 4; ++k) ss += dot4(cur[k], cur[k]);
    ss = wave_reduce_sum(ss);
    const float wgt = 1.0f / fmaxf(sqrtf(ss), EPS);

#pragma unroll
    for (int k = 0; k < 4; ++k) {
      zs[k].x += cur[k].x; zs[k].y += cur[k].y; zs[k].z += cur[k].z; zs[k].w += cur[k].w;
      uu[k].x += wgt * cur[k].x; uu[k].y += wgt * cur[k].y;
      uu[k].z += wgt * cur[k].z; uu[k].w += wgt * cur[k].w;
    }
#pragma unroll
    for (int k = 0; k < 4; ++k) cur[k] = nxt[k];
  }

  // cross-wave combine
#pragma unroll
  for (int k = 0; k < 4; ++k) {
    lds_zs[w][k * 64 + lane] = zs[k];
    lds_uu[w][k * 64 + lane] = uu[k];
  }
  __syncthreads();

  float4 zsum = make_float4(0.f, 0.f, 0.f, 0.f);
  float4 usum = make_float4(0.f, 0.f, 0.f, 0.f);
  if (t < 256) {
#pragma unroll
    for (int ww = 0; ww < WAVES; ++ww) {
      float4 a = lds_zs[ww][t];
      float4 u = lds_uu[ww][t];
      zsum.x += a.x; zsum.y += a.y; zsum.z += a.z; zsum.w += a.w;
      usum.x += u.x; usum.y += u.y; usum.z += u.z; usum.w += u.w;
    }
    float ssq = wave_reduce_sum(dot4(zsum, zsum));
    if (lane == 0) red[w] = ssq;  // w in 0..3 here
  }
  __syncthreads();
  if (t < 256) {
    const float ss2 = red[0] + red[1] + red[2] + red[3];
    // an = (z_sum/P)/max(||z_sum||/P, eps) = z_sum / max(||z_sum||, P*eps)
    const float inv = 1.0f / fmaxf(sqrtf(ss2), (float)P * EPS);
    float4 a4 = make_float4(zsum.x * inv, zsum.y * inv, zsum.z * inv, zsum.w * inv);

    ((float4*)an)[(size_t)b * D4 + t] = a4;
    ((float4*)Uv)[(size_t)b * D4 + t] = usum;

    float dg = wave_reduce_sum(dot4(usum, a4));
    if (lane == 0) red[4 + w] = dg;
  }
  __syncthreads();
  if (t == 0) diag[b] = red[4] + red[5] + red[6] + red[7];
}

// K_tail: 32 blocks. Each block column-sums an/Uv over its 16 b's, atomically
// accumulates into Sfin/Tfin (device-scope), adds its diag partial, then the
// last block (semaphore) computes out = (S.T - sum diag)/count - 1.
__global__ __launch_bounds__(256) void k_tail(const float* __restrict__ an,
                                              const float* __restrict__ Uv,
                                              const float* __restrict__ diag,
                                              float* __restrict__ Sfin,
                                              float* __restrict__ Tfin,
                                              float* __restrict__ diagsum,
                                              int* __restrict__ counter,
                                              float* __restrict__ out) {
  const int blk = blockIdx.x;
  const int t = threadIdx.x;  // owns float4 index t, D4 == 256

  float4 s = make_float4(0.f, 0.f, 0.f, 0.f);
  float4 tt = make_float4(0.f, 0.f, 0.f, 0.f);
#pragma unroll 4
  for (int i = 0; i < BPB; ++i) {
    const size_t b = (size_t)blk * BPB + i;
    float4 a = ((const float4*)an)[b * D4 + t];
    float4 u = ((const float4*)Uv)[b * D4 + t];
    s.x += a.x; s.y += a.y; s.z += a.z; s.w += a.w;
    tt.x += u.x; tt.y += u.y; tt.z += u.z; tt.w += u.w;
  }
  atomicAdd(&Sfin[4 * t + 0], s.x);
  atomicAdd(&Sfin[4 * t + 1], s.y);
  atomicAdd(&Sfin[4 * t + 2], s.z);
  atomicAdd(&Sfin[4 * t + 3], s.w);
  atomicAdd(&Tfin[4 * t + 0], tt.x);
  atomicAdd(&Tfin[4 * t + 1], tt.y);
  atomicAdd(&Tfin[4 * t + 2], tt.z);
  atomicAdd(&Tfin[4 * t + 3], tt.w);

  // diag partial: lanes 0..15 of wave 0 load, wave-reduce, one atomic
  if (t < 64) {
    float dv = (t < BPB) ? diag[blk * BPB + t] : 0.f;
    dv = wave_reduce_sum(dv);
    if (t == 0) atomicAdd(diagsum, dv);
  }

  __threadfence();   // every thread: make my atomics/stores device-visible
  __syncthreads();

  __shared__ int is_last;
  if (t == 0) {
    int old = atomicAdd(counter, 1);
    is_last = (old == K3B - 1);
  }
  __syncthreads();
  if (!is_last) return;

  // finalize: all other blocks' atomics are visible (they fenced before bump)
  __threadfence();
  float local = 0.f;
#pragma unroll
  for (int k = 0; k < 4; ++k) {
    float sv = __hip_atomic_load(&Sfin[4 * t + k], __ATOMIC_RELAXED, __HIP_MEMORY_SCOPE_AGENT);
    float tv = __hip_atomic_load(&Tfin[4 * t + k], __ATOMIC_RELAXED, __HIP_MEMORY_SCOPE_AGENT);
    local += sv * tv;
  }
  local = wave_reduce_sum(local);
  __shared__ float red2[4];
  if ((t & 63) == 0) red2[t >> 6] = local;
  __syncthreads();
  if (t == 0) {
    const float dot = red2[0] + red2[1] + red2[2] + red2[3];
    const float dsum = __hip_atomic_load(diagsum, __ATOMIC_RELAXED, __HIP_MEMORY_SCOPE_AGENT);
    const float count = 64.0f * 512.0f * 511.0f;  // P*B*(B-1), exact in fp32
    out[0] = (dot - dsum) / count - 1.0f;
  }
}

extern "C" void kernel_launch(void* const* d_in, const int* in_sizes, int n_in,
                              void* d_out, int out_size, void* d_ws, size_t ws_size,
                              hipStream_t stream) {
  const float* z = (const float*)d_in[0];  // z_list (P,B,D); d_in[1] unused

  float* ws = (float*)d_ws;
  float* an = ws;                                  // B*D
  float* Uv = an + (size_t)B * D;                  // B*D
  float* diag = Uv + (size_t)B * D;                // B
  float* Sfin = diag + B;                          // D
  float* Tfin = Sfin + D;                          // D
  float* extras = Tfin + D;                        // 4 floats: [0]=diagsum, [1]=counter
  float* diagsum = extras;
  int* counter = (int*)(extras + 1);
  float4* zero4 = (float4*)Sfin;                   // covers Sfin,Tfin,extras = 513 float4

  k_main<<<B, 512, 0, stream>>>(z, an, Uv, diag, zero4);
  k_tail<<<K3B, 256, 0, stream>>>(an, Uv, diag, Sfin, Tfin, diagsum, counter, (float*)d_out);
}

// Round 4
// 35.215 us; speedup vs baseline: 1.1736x; 1.1736x over previous
//
#include <hip/hip_runtime.h>
#include <math.h>

// Problem constants (from reference setup_inputs): z_list (P,B,D) fp32
constexpr int P = 64, B = 512, D = 1024;
constexpr int D4 = D / 4;           // 256 float4 per row
constexpr int WAVES = 4;            // waves per block in main kernel
constexpr int PC = P / WAVES;       // 16 p-rows per wave (8 pairs)
constexpr int K3B = 32;             // blocks in S/T partial-sum kernel
constexpr int BPB = B / K3B;        // 16 b's per K3 block
#define EPS 1e-8f

__device__ inline float wave_reduce_sum(float v) {
#pragma unroll
  for (int off = 1; off < 64; off <<= 1) v += __shfl_xor(v, off);
  return v;
}

__device__ inline float dot4(const float4& a, const float4& b) {
  return a.x * b.x + a.y * b.y + a.z * b.z + a.w * b.w;
}

// K_main: one block (4 waves) per b. Each wave streams 16 p-rows of z[:,b,:]
// as 8 row-PAIRS: next pair prefetched depth-1 (8 KB in flight per wave),
// two independent norm-reduce chains interleaved for ILP. LDS combines the
// 4 waves; block normalizes mean row -> an[b], writes Uv[b], diag[b]=Uv.an.
__global__ __launch_bounds__(256) void k_main(const float* __restrict__ z,
                                              float* __restrict__ an,
                                              float* __restrict__ Uv,
                                              float* __restrict__ diag) {
  const int b = blockIdx.x;
  const int t = threadIdx.x;
  const int w = t >> 6;              // wave 0..3
  const int lane = t & 63;

  __shared__ float4 lds_zs[WAVES][D4];  // 16 KB
  __shared__ float4 lds_uu[WAVES][D4];  // 16 KB
  __shared__ float red[2 * WAVES];

  float4 zs[4], uu[4];
#pragma unroll
  for (int k = 0; k < 4; ++k) {
    zs[k] = make_float4(0.f, 0.f, 0.f, 0.f);
    uu[k] = make_float4(0.f, 0.f, 0.f, 0.f);
  }

  // wave w handles p = w*PC .. w*PC+PC-1, rows z[p][b][:]
  const size_t pstride = (size_t)B * D4;  // float4 stride between p's
  const float4* base = (const float4*)z + ((size_t)(w * PC) * B + b) * D4;

  float4 curA[4], curB[4];
#pragma unroll
  for (int k = 0; k < 4; ++k) {
    curA[k] = base[k * 64 + lane];
    curB[k] = base[pstride + k * 64 + lane];
  }

  for (int pr = 0; pr < PC / 2; ++pr) {
    float4 nxtA[4], nxtB[4];
    const bool more = (pr + 1 < PC / 2);
    if (more) {
      const float4* nA = base + (size_t)(2 * pr + 2) * pstride;
      const float4* nB = base + (size_t)(2 * pr + 3) * pstride;
#pragma unroll
      for (int k = 0; k < 4; ++k) {
        nxtA[k] = nA[k * 64 + lane];
        nxtB[k] = nB[k * 64 + lane];
      }
    }

    // two independent norm reductions, interleaved for ILP
    float ssA = 0.f, ssB = 0.f;
#pragma unroll
    for (int k = 0; k < 4; ++k) {
      ssA += dot4(curA[k], curA[k]);
      ssB += dot4(curB[k], curB[k]);
    }
#pragma unroll
    for (int off = 1; off < 64; off <<= 1) {
      ssA += __shfl_xor(ssA, off);
      ssB += __shfl_xor(ssB, off);
    }
    const float wA = 1.0f / fmaxf(sqrtf(ssA), EPS);
    const float wB = 1.0f / fmaxf(sqrtf(ssB), EPS);

#pragma unroll
    for (int k = 0; k < 4; ++k) {
      zs[k].x += curA[k].x + curB[k].x;
      zs[k].y += curA[k].y + curB[k].y;
      zs[k].z += curA[k].z + curB[k].z;
      zs[k].w += curA[k].w + curB[k].w;
      uu[k].x += wA * curA[k].x + wB * curB[k].x;
      uu[k].y += wA * curA[k].y + wB * curB[k].y;
      uu[k].z += wA * curA[k].z + wB * curB[k].z;
      uu[k].w += wA * curA[k].w + wB * curB[k].w;
    }
    if (more) {
#pragma unroll
      for (int k = 0; k < 4; ++k) {
        curA[k] = nxtA[k];
        curB[k] = nxtB[k];
      }
    }
  }

  // cross-wave combine: wave w's float4 index k*64+lane
#pragma unroll
  for (int k = 0; k < 4; ++k) {
    lds_zs[w][k * 64 + lane] = zs[k];
    lds_uu[w][k * 64 + lane] = uu[k];
  }
  __syncthreads();

  // thread t now owns float4 index t (d = 4t..4t+3)
  float4 zsum = make_float4(0.f, 0.f, 0.f, 0.f);
  float4 usum = make_float4(0.f, 0.f, 0.f, 0.f);
#pragma unroll
  for (int ww = 0; ww < WAVES; ++ww) {
    float4 a = lds_zs[ww][t];
    float4 u = lds_uu[ww][t];
    zsum.x += a.x; zsum.y += a.y; zsum.z += a.z; zsum.w += a.w;
    usum.x += u.x; usum.y += u.y; usum.z += u.z; usum.w += u.w;
  }

  // ||z_sum||^2 across the block, broadcast
  float ss = dot4(zsum, zsum);
  ss = wave_reduce_sum(ss);
  if (lane == 0) red[w] = ss;
  __syncthreads();
  ss = red[0] + red[1] + red[2] + red[3];

  // an = (z_sum/P)/max(||z_sum||/P, eps) = z_sum / max(||z_sum||, P*eps)
  const float inv = 1.0f / fmaxf(sqrtf(ss), (float)P * EPS);
  float4 a4 = make_float4(zsum.x * inv, zsum.y * inv, zsum.z * inv, zsum.w * inv);

  ((float4*)an)[(size_t)b * D4 + t] = a4;
  ((float4*)Uv)[(size_t)b * D4 + t] = usum;

  float dg = dot4(usum, a4);
  dg = wave_reduce_sum(dg);
  if (lane == 0) red[WAVES + w] = dg;
  __syncthreads();
  if (t == 0) diag[b] = red[WAVES] + red[WAVES + 1] + red[WAVES + 2] + red[WAVES + 3];
}

// K3: partial column-sums of an and Uv over b-chunks -> Spart/Tpart [K3B][D]
__global__ __launch_bounds__(256) void k3_colsum(const float* __restrict__ an,
                                                 const float* __restrict__ Uv,
                                                 float* __restrict__ Spart,
                                                 float* __restrict__ Tpart) {
  const int blk = blockIdx.x;
  const int t = threadIdx.x;
  float4 s = make_float4(0.f, 0.f, 0.f, 0.f);
  float4 tt = make_float4(0.f, 0.f, 0.f, 0.f);
#pragma unroll 4
  for (int i = 0; i < BPB; ++i) {
    const size_t b = (size_t)blk * BPB + i;
    float4 a = ((const float4*)an)[b * D4 + t];
    float4 u = ((const float4*)Uv)[b * D4 + t];
    s.x += a.x; s.y += a.y; s.z += a.z; s.w += a.w;
    tt.x += u.x; tt.y += u.y; tt.z += u.z; tt.w += u.w;
  }
  ((float4*)Spart)[(size_t)blk * D4 + t] = s;
  ((float4*)Tpart)[(size_t)blk * D4 + t] = tt;
}

// K4: final combine. S = sum Spart, T = sum Tpart, out = (S.T - sum diag)/count - 1
__global__ __launch_bounds__(256) void k4_final(const float* __restrict__ Spart,
                                                const float* __restrict__ Tpart,
                                                const float* __restrict__ diag,
                                                float* __restrict__ out) {
  const int t = threadIdx.x;
  __shared__ float red[4];
  float4 S = make_float4(0.f, 0.f, 0.f, 0.f);
  float4 T = make_float4(0.f, 0.f, 0.f, 0.f);
#pragma unroll 4
  for (int blk = 0; blk < K3B; ++blk) {
    float4 s = ((const float4*)Spart)[(size_t)blk * D4 + t];
    float4 u = ((const float4*)Tpart)[(size_t)blk * D4 + t];
    S.x += s.x; S.y += s.y; S.z += s.z; S.w += s.w;
    T.x += u.x; T.y += u.y; T.z += u.z; T.w += u.w;
  }
  float local = dot4(S, T) - diag[t] - diag[t + 256];
  local = wave_reduce_sum(local);
  const int wid = t >> 6;
  if ((t & 63) == 0) red[wid] = local;
  __syncthreads();
  if (t == 0) {
    const float tot = red[0] + red[1] + red[2] + red[3];
    const float count = 64.0f * 512.0f * 511.0f;  // P*B*(B-1), exact in fp32
    out[0] = tot / count - 1.0f;
  }
}

extern "C" void kernel_launch(void* const* d_in, const int* in_sizes, int n_in,
                              void* d_out, int out_size, void* d_ws, size_t ws_size,
                              hipStream_t stream) {
  const float* z = (const float*)d_in[0];  // z_list (P,B,D); d_in[1] unused

  float* ws = (float*)d_ws;
  float* an = ws;                                  // B*D
  float* Uv = an + (size_t)B * D;                  // B*D
  float* diag = Uv + (size_t)B * D;                // B
  float* Spart = diag + B;                         // K3B*D
  float* Tpart = Spart + (size_t)K3B * D;          // K3B*D

  k_main<<<B, 256, 0, stream>>>(z, an, Uv, diag);
  k3_colsum<<<K3B, 256, 0, stream>>>(an, Uv, Spart, Tpart);
  k4_final<<<1, 256, 0, stream>>>(Spart, Tpart, diag, (float*)d_out);
}